// Round 1
// 250.393 us; speedup vs baseline: 1.0510x; 1.0510x over previous
//
#include <hip/hip_runtime.h>
#include <hip/hip_fp16.h>
#include <math.h>

// PerBandSoftAGC: out = x / (clip(EMA_FIR(|x|), eps)^alpha + delta)
// EMA FIR (L=100 taps j=0..99, geometric) via exact sliding recursion:
//   M[t] = q*M[t-1] + w0*|x[t]| - w0*q^100 * |x[t-100]|
// R3: fp16 LDS row (17.4 KB) -> 8 blocks/CU; paired __half2 reads; +2/32 skew.
// R4: replace per-thread 99-tap init loop (~40% of compute VALU, plus a
//     divergent row-start path) with an exact chunk-prefix decomposition:
//       M[t0-1] = w0*( P_{k-1} + q^32 P_{k-2} + q^64 P_{k-3} + q^96*corr4 )
//     where P_k = sum_i q^{31-i}|x[32k+i]| is computed by each thread over its
//     OWN chunk (kept in 16 half2 registers, reused by the main loop) and
//     shared via a small LDS array (one extra barrier). A 104-half zero pad at
//     the front of the LDS row makes tail-drop reads and the init corrections
//     branchless for every thread -> single uniform code path, no divergence.

constexpr int T      = 8192;
constexpr int KC_    = 128;
constexpr int LEN    = 100;
constexpr int BLOCK  = 256;
constexpr int CHUNK  = 32;          // T / BLOCK
constexpr int PAD    = 104;         // zero history pad: >= LEN, even, mult of 8
constexpr int TP     = T + PAD;     // 8296 halves before skew
constexpr float EPS_   = 1e-6f;
constexpr float DELTA_ = 0.1f;
constexpr float LOG2E  = 1.4426950408889634f;

// skew: +2 halves per 32 halves; preserves parity so even-element half2 stays
// 4B aligned; lane stride for chunk reads = 68 B = 17 words, gcd(17,32)=1 ->
// exact 2-way (free) bank distribution.
__device__ __forceinline__ int sk(int t) { return t + ((t >> 5) << 1); }

__device__ __forceinline__ float fast_sigmoid(float x) {
    const float e = __builtin_amdgcn_exp2f(-x * LOG2E);
    return __builtin_amdgcn_rcpf(1.0f + e);
}

__device__ __forceinline__ float gain_div(float xv, float M, float alpha) {
    const float Mc = fmaxf(M, EPS_);
    // Mc^alpha = exp2(alpha * log2(Mc)); v_log_f32 is log2, v_exp_f32 is exp2
    const float g  = __builtin_amdgcn_exp2f(alpha * __builtin_amdgcn_logf(Mc)) + DELTA_;
    return xv * __builtin_amdgcn_rcpf(g);   // g >= delta = 0.1, rcp safe
}

__global__ __launch_bounds__(BLOCK, 8) void agc_kernel(
    const float* __restrict__ x,
    const float* __restrict__ alpha_raw,
    const float* __restrict__ log_s,
    float* __restrict__ out)
{
    __shared__ __half lh[TP + ((TP >> 5) << 1)];   // 8814 halves = 17628 B
    __shared__ float  Pe[BLOCK + 3];               // chunk prefixes, 3 lead zeros

    const int row = blockIdx.x;
    const int kc  = row & (KC_ - 1);
    const int tid = threadIdx.x;
    const float* __restrict__ xrow = x + (size_t)row * T;
    float* __restrict__ orow       = out + (size_t)row * T;

    // ---- zero history pad (indices 0..PAD-1) + P lead zeros ----
    if (tid < PAD / 2)
        *reinterpret_cast<__half2*>(&lh[sk(2 * tid)]) =
            __float22half2_rn(make_float2(0.0f, 0.0f));
    if (tid < 3) Pe[tid] = 0.0f;

    // ---- stage row into skewed fp16 LDS (coalesced float4 global reads) ----
    #pragma unroll
    for (int it = 0; it < (T / 4) / BLOCK; ++it) {
        const int i = tid + it * BLOCK;
        const float4 v = reinterpret_cast<const float4*>(xrow)[i];
        const int e = sk(PAD + i * 4);  // 4 halves never cross a 32-group
        *reinterpret_cast<__half2*>(&lh[e])     = __float22half2_rn(make_float2(v.x, v.y));
        *reinterpret_cast<__half2*>(&lh[e + 2]) = __float22half2_rn(make_float2(v.z, v.w));
    }

    // ---- per-channel scalars (block-uniform) ----
    const float s     = fast_sigmoid(log_s[kc]);
    const float alpha = 0.5f * fast_sigmoid(alpha_raw[kc]);
    const float q     = 1.0f - s;
    const float lq    = __builtin_amdgcn_logf(q);          // log2(q)
    const float q32   = __builtin_amdgcn_exp2f(32.0f * lq);
    const float q64   = q32 * q32;
    const float q96   = q64 * q32;
    const float q100  = __builtin_amdgcn_exp2f(100.0f * lq);
    const float norm  = (1.0f - q100) + 1e-8f;   // sum of unnormalized weights
    const float w0    = s / norm;                // normalized weight j=0
    const float c3    = w0 * q100;               // tail-drop coefficient

    __syncthreads();

    const int t0 = tid * CHUNK;

    // paired fp16 read: elements (t, t+1), t even; t may be negative down to
    // -LEN (lands in the zero pad)
    auto ld2 = [&](int t) -> float2 {
        return __half22float2(*reinterpret_cast<const __half2*>(&lh[sk(PAD + t)]));
    };

    // ---- own chunk pairs -> registers (reused in P pass and main loop) ----
    __half2 h2[CHUNK / 2];
    #pragma unroll
    for (int i = 0; i < CHUNK / 2; ++i)
        h2[i] = *reinterpret_cast<const __half2*>(&lh[sk(PAD + t0 + 2 * i)]);

    // ---- chunk prefix P_k = sum_{i=0..31} q^{31-i} |x[t0+i]| ----
    float P = 0.0f;
    const float qq = q * q;
    #pragma unroll
    for (int i = 0; i < CHUNK / 2; ++i) {
        const float2 f = __half22float2(h2[i]);
        P = fmaf(qq, P, fmaf(q, fabsf(f.x), fabsf(f.y)));
    }
    Pe[3 + tid] = P;
    __syncthreads();

    // ---- exact init: M[t0-1] over the 100-tap window (zeros where OOB) ----
    // corr4 = |x[t0-97]| + q|x[t0-98]| + q^2|x[t0-99]| + q^3|x[t0-100]|
    const float2 pA = ld2(t0 - 100);   // (x[t0-100], x[t0-99])
    const float2 pB = ld2(t0 - 98);    // (x[t0-98],  x[t0-97])
    float corr = fmaf(q, fabsf(pA.x), fabsf(pA.y));
    corr = fmaf(q, corr, fabsf(pB.x));
    corr = fmaf(q, corr, fabsf(pB.y));
    float h = fmaf(q32, Pe[1 + tid], Pe[2 + tid]);   // P_{k-1} + q32*P_{k-2}
    h = fmaf(q64, Pe[tid], h);                       // + q64*P_{k-3}
    h = fmaf(q96, corr, h);                          // + q96*corr4
    float M = w0 * h;                                // == M[t0-1], exact

    // ---- main loop: uniform path for ALL threads (pad supplies zeros) ----
    float o[4];
    #pragma unroll
    for (int m = 0; m < CHUNK / 2; ++m) {
        const float2 xf = __half22float2(h2[m]);    // own elements 2m, 2m+1
        const float2 xb = ld2(t0 - LEN + 2 * m);    // tail-drop pair
        M = fmaf(q, M, fmaf(w0, fabsf(xf.x), -c3 * fabsf(xb.x)));
        o[(2 * m)     & 3] = gain_div(xf.x, M, alpha);
        M = fmaf(q, M, fmaf(w0, fabsf(xf.y), -c3 * fabsf(xb.y)));
        o[(2 * m + 1) & 3] = gain_div(xf.y, M, alpha);
        if (m & 1)
            reinterpret_cast<float4*>(orow)[(t0 >> 2) + (m >> 1)] =
                make_float4(o[0], o[1], o[2], o[3]);
    }
}

extern "C" void kernel_launch(void* const* d_in, const int* in_sizes, int n_in,
                              void* d_out, int out_size, void* d_ws, size_t ws_size,
                              hipStream_t stream) {
    const float* x         = (const float*)d_in[0];
    const float* alpha_raw = (const float*)d_in[1];
    const float* log_s     = (const float*)d_in[2];
    float* out             = (float*)d_out;
    const int nrows = in_sizes[0] / T;   // B*KC = 4096
    agc_kernel<<<nrows, BLOCK, 0, stream>>>(x, alpha_raw, log_s, out);
}

// Round 2
// 227.561 us; speedup vs baseline: 1.1564x; 1.1003x over previous
//
#include <hip/hip_runtime.h>
#include <hip/hip_fp16.h>
#include <math.h>

// PerBandSoftAGC: out = x / (clip(EMA_FIR(|x|), eps)^alpha + delta)
// EMA FIR (L=100 taps j=0..99, geometric) via exact sliding recursion:
//   M[t] = q*M[t-1] + w0*|x[t]| - w0*q^100 * |x[t-100]|
// R3: fp16 LDS row; paired __half2 reads; +2/32 skew.
// R4: chunk-prefix init  M[t0-1] = w0 * sum_i q^{4?}(P-chunks)  (exact).
// R5: CHUNK 32 -> 4. Rocprof showed the non-VALU residual (~72us) unchanged
//     across R3->R4: the bottleneck is the scattered global stores (each
//     dwordx4 store had lanes at 128B stride = 64 cache lines/instr). With
//     4-element ownership, each thread's output IS one float4 -> loads AND
//     stores perfectly coalesced; own chunk arrives in registers from the
//     global load (no LDS read-back); init is a 25-term Horner over chunk
//     prefixes P_c = sum q^{3-i}|x[4c+i]| shared via a tiny Pe[] array.
//     One barrier per block; LDS ~6.7KB; halo overhead 100/2048 = 4.9%.

constexpr int T      = 8192;
constexpr int KC_    = 128;
constexpr int LEN    = 100;
constexpr int BLOCK  = 512;
constexpr int CHUNK  = 4;
constexpr int SEG    = BLOCK * CHUNK;   // 2048 elements per block
constexpr int NSEG   = T / SEG;         // 4 blocks per row
constexpr int PAD    = LEN;             // staged halo = exactly 25 chunks
constexpr int NHALO  = PAD / CHUNK;     // 25
constexpr int TP     = SEG + PAD;       // 2148 halves before skew
constexpr float EPS_   = 1e-6f;
constexpr float DELTA_ = 0.1f;
constexpr float LOG2E  = 1.4426950408889634f;

// skew: +2 halves per 32 halves; parity-preserving so even-element half2
// stays 4B aligned; within a 32-group sk is linear (sk(e+k)=sk(e)+k).
__device__ __forceinline__ int sk(int t) { return t + ((t >> 5) << 1); }

__device__ __forceinline__ float fast_sigmoid(float x) {
    const float e = __builtin_amdgcn_exp2f(-x * LOG2E);
    return __builtin_amdgcn_rcpf(1.0f + e);
}

__device__ __forceinline__ float gain_div(float xv, float M, float alpha) {
    const float Mc = fmaxf(M, EPS_);
    // Mc^alpha = exp2(alpha * log2(Mc)); v_log_f32 is log2, v_exp_f32 is exp2
    const float g  = __builtin_amdgcn_exp2f(alpha * __builtin_amdgcn_logf(Mc)) + DELTA_;
    return xv * __builtin_amdgcn_rcpf(g);   // g >= delta = 0.1, rcp safe
}

__global__ __launch_bounds__(BLOCK, 8) void agc_kernel(
    const float* __restrict__ x,
    const float* __restrict__ alpha_raw,
    const float* __restrict__ log_s,
    float* __restrict__ out)
{
    __shared__ __half lh[TP + ((TP >> 5) << 1)];   // 2282 halves = 4564 B
    __shared__ float  Pe[NHALO + BLOCK];           // chunk prefixes (+25 halo)

    const int bid = blockIdx.x;
    const int row = bid >> 2;              // NSEG = 4
    const int seg = bid & (NSEG - 1);      // consecutive blocks share a row -> L2 locality
    const int g0  = seg * SEG;             // segment start within row
    const int kc  = row & (KC_ - 1);
    const int tid = threadIdx.x;
    const float* __restrict__ xrow = x + (size_t)row * T;
    float* __restrict__ orow       = out + (size_t)row * T;

    // ---- per-channel scalars (block-uniform) ----
    const float s     = fast_sigmoid(log_s[kc]);
    const float alpha = 0.5f * fast_sigmoid(alpha_raw[kc]);
    const float q     = 1.0f - s;
    const float lq    = __builtin_amdgcn_logf(q);          // log2(q)
    const float qq    = q * q;
    const float q4    = qq * qq;
    const float q100  = __builtin_amdgcn_exp2f(100.0f * lq);
    const float norm  = (1.0f - q100) + 1e-8f;   // sum of unnormalized weights
    const float w0    = s / norm;                // normalized weight j=0
    const float c3    = w0 * q100;               // tail-drop coefficient

    const int t0 = tid * CHUNK;                  // segment-local start

    // ---- own chunk: one coalesced float4 load; fp16-round for consistency ----
    const float4 v = reinterpret_cast<const float4*>(xrow)[(g0 >> 2) + tid];
    const __half2 ha = __float22half2_rn(make_float2(v.x, v.y));
    const __half2 hb = __float22half2_rn(make_float2(v.z, v.w));
    {   // stage to skewed fp16 LDS (4 halves never cross a 32-group: (100+4t)%32<=28)
        const int e = sk(PAD + t0);
        *reinterpret_cast<__half2*>(&lh[e])     = ha;
        *reinterpret_cast<__half2*>(&lh[e + 2]) = hb;
    }
    const float2 fA = __half22float2(ha);
    const float2 fB = __half22float2(hb);
    const float a0 = fabsf(fA.x), a1 = fabsf(fA.y);
    const float a2 = fabsf(fB.x), a3 = fabsf(fB.y);
    // chunk prefix P = q^3|x0| + q^2|x1| + q|x2| + |x3|
    Pe[NHALO + tid] = fmaf(q, fmaf(q, fmaf(q, a0, a1), a2), a3);

    // ---- halo: previous 100 elements (zeros at row start) ----
    if (tid < NHALO) {
        float4 hv = make_float4(0.0f, 0.0f, 0.0f, 0.0f);
        if (seg != 0)
            hv = reinterpret_cast<const float4*>(xrow)[((g0 - PAD) >> 2) + tid];
        const __half2 h0 = __float22half2_rn(make_float2(hv.x, hv.y));
        const __half2 h1 = __float22half2_rn(make_float2(hv.z, hv.w));
        const int e = sk(CHUNK * tid);
        *reinterpret_cast<__half2*>(&lh[e])     = h0;
        *reinterpret_cast<__half2*>(&lh[e + 2]) = h1;
        const float2 f0 = __half22float2(h0);
        const float2 f1 = __half22float2(h1);
        Pe[tid] = fmaf(q, fmaf(q, fmaf(q, fabsf(f0.x), fabsf(f0.y)), fabsf(f1.x)),
                       fabsf(f1.y));
    }

    __syncthreads();

    // ---- exact init via Horner over 25 chunk prefixes (100 taps exactly):
    //      M[t0-1] = w0 * sum_{i=1..25} q^{4(i-1)} * P[tid-i]
    //      Pe reads: indices tid..tid+24 -> base + imm offsets, 2-way (free) banks
    float acc = Pe[tid];                          // i = 25
    #pragma unroll
    for (int i = 24; i >= 1; --i)
        acc = fmaf(acc, q4, Pe[NHALO + tid - i]);
    float M = w0 * acc;                           // == M[t0-1], exact

    // ---- tail-drop pair: elements t0-100..t0-97 live at lh[sk(t0)] ----
    const int eb = sk(t0);
    const float2 tb0 = __half22float2(*reinterpret_cast<const __half2*>(&lh[eb]));
    const float2 tb1 = __half22float2(*reinterpret_cast<const __half2*>(&lh[eb + 2]));

    // ---- 4-step recursion + gain; output is one coalesced float4 ----
    float4 o;
    M = fmaf(q, M, fmaf(w0, a0, -c3 * fabsf(tb0.x)));
    o.x = gain_div(fA.x, M, alpha);
    M = fmaf(q, M, fmaf(w0, a1, -c3 * fabsf(tb0.y)));
    o.y = gain_div(fA.y, M, alpha);
    M = fmaf(q, M, fmaf(w0, a2, -c3 * fabsf(tb1.x)));
    o.z = gain_div(fB.x, M, alpha);
    M = fmaf(q, M, fmaf(w0, a3, -c3 * fabsf(tb1.y)));
    o.w = gain_div(fB.y, M, alpha);

    reinterpret_cast<float4*>(orow)[(g0 >> 2) + tid] = o;
}

extern "C" void kernel_launch(void* const* d_in, const int* in_sizes, int n_in,
                              void* d_out, int out_size, void* d_ws, size_t ws_size,
                              hipStream_t stream) {
    const float* x         = (const float*)d_in[0];
    const float* alpha_raw = (const float*)d_in[1];
    const float* log_s     = (const float*)d_in[2];
    float* out             = (float*)d_out;
    const int nrows = in_sizes[0] / T;   // B*KC = 4096
    agc_kernel<<<nrows * NSEG, BLOCK, 0, stream>>>(x, alpha_raw, log_s, out);
}

// Round 3
// 224.645 us; speedup vs baseline: 1.1714x; 1.0130x over previous
//
#include <hip/hip_runtime.h>
#include <math.h>

// PerBandSoftAGC: out = x / (clip(EMA_FIR(|x|), eps)^alpha + delta)
// EMA FIR (L=100 taps j=0..99, geometric) via exact sliding recursion:
//   M[t] = q*M[t-1] + w0*|x[t]| - w0*q^100 * |x[t-100]|
// R5: CHUNK=4 ownership -> coalesced float4 loads/stores; chunk-prefix init
//     M[t0-1] = w0 * Horner_25(P-chunks)  (exact, one barrier).
// R6: drop the staged LDS row entirely. Each thread's tail-drop chunk is the
//     float4 at index (g0>>2)+tid-25: a second coalesced GLOBAL load that is
//     L1/L2-hot for tid>=25 (aliases lines loaded by lane tid-25) and doubles
//     as the halo-prefix source for tid<25. Removes all fp16 converts, LDS
//     staging writes, skew math, and tail LDS reads; LDS is now just Pe[537]
//     (2.1 KB). Full-fp32 path (telescoping still exact: add & drop use the
//     identical fp32 value). Horner split even/odd (q^8 step) to halve the
//     init dependency chain. Non-temporal store for the write-once output.

constexpr int T      = 8192;
constexpr int KC_    = 128;
constexpr int LEN    = 100;
constexpr int BLOCK  = 512;
constexpr int CHUNK  = 4;
constexpr int SEG    = BLOCK * CHUNK;   // 2048 elements per block
constexpr int NSEG   = T / SEG;         // 4 blocks per row
constexpr int NHALO  = LEN / CHUNK;     // 25 chunks of history
constexpr float EPS_   = 1e-6f;
constexpr float DELTA_ = 0.1f;
constexpr float LOG2E  = 1.4426950408889634f;

typedef float f32x4 __attribute__((ext_vector_type(4)));

__device__ __forceinline__ float fast_sigmoid(float x) {
    const float e = __builtin_amdgcn_exp2f(-x * LOG2E);
    return __builtin_amdgcn_rcpf(1.0f + e);
}

__device__ __forceinline__ float gain_div(float xv, float M, float alpha) {
    const float Mc = fmaxf(M, EPS_);
    // Mc^alpha = exp2(alpha * log2(Mc)); v_log_f32 is log2, v_exp_f32 is exp2
    const float g  = __builtin_amdgcn_exp2f(alpha * __builtin_amdgcn_logf(Mc)) + DELTA_;
    return xv * __builtin_amdgcn_rcpf(g);   // g >= delta = 0.1, rcp safe
}

__global__ __launch_bounds__(BLOCK, 8) void agc_kernel(
    const float* __restrict__ x,
    const float* __restrict__ alpha_raw,
    const float* __restrict__ log_s,
    float* __restrict__ out)
{
    __shared__ float Pe[NHALO + BLOCK];    // chunk prefixes (+25 halo) = 2148 B

    const int bid = blockIdx.x;
    const int row = bid >> 2;              // NSEG = 4
    const int seg = bid & (NSEG - 1);      // consecutive blocks share a row
    const int g0  = seg * SEG;             // segment start within row
    const int kc  = row & (KC_ - 1);
    const int tid = threadIdx.x;
    const float* __restrict__ xrow = x + (size_t)row * T;
    float* __restrict__ orow       = out + (size_t)row * T;

    // ---- per-channel scalars (block-uniform) ----
    const float s     = fast_sigmoid(log_s[kc]);
    const float alpha = 0.5f * fast_sigmoid(alpha_raw[kc]);
    const float q     = 1.0f - s;
    const float lq    = __builtin_amdgcn_logf(q);          // log2(q)
    const float qq    = q * q;
    const float q4    = qq * qq;
    const float q8    = q4 * q4;
    const float q100  = __builtin_amdgcn_exp2f(100.0f * lq);
    const float norm  = (1.0f - q100) + 1e-8f;   // sum of unnormalized weights
    const float w0    = s / norm;                // normalized weight j=0
    const float c3    = w0 * q100;               // tail-drop coefficient

    const int i4 = (g0 >> 2) + tid;        // own float4 index within row

    // ---- own chunk + tail-drop chunk: two coalesced float4 loads ----
    const f32x4 v = reinterpret_cast<const f32x4*>(xrow)[i4];
    f32x4 pv = {0.0f, 0.0f, 0.0f, 0.0f};
    if (seg != 0 || tid >= NHALO)          // zeros before row start (conv pad)
        pv = reinterpret_cast<const f32x4*>(xrow)[i4 - NHALO];

    const float a0 = fabsf(v.x),  a1 = fabsf(v.y),  a2 = fabsf(v.z),  a3 = fabsf(v.w);
    const float b0 = fabsf(pv.x), b1 = fabsf(pv.y), b2 = fabsf(pv.z), b3 = fabsf(pv.w);

    // chunk prefix P = q^3|x0| + q^2|x1| + q|x2| + |x3|
    Pe[NHALO + tid] = fmaf(q, fmaf(q, fmaf(q, a0, a1), a2), a3);
    if (tid < NHALO)                       // pv IS halo chunk tid here
        Pe[tid] = fmaf(q, fmaf(q, fmaf(q, b0, b1), b2), b3);

    __syncthreads();

    // ---- exact init over 25 chunk prefixes (100 taps exactly):
    //      M[t0-1] = w0 * sum_{j=0..24} q^{4(24-j)} * Pe[tid+j]
    //      split even/odd j (step q^8) -> two ~12-FMA chains, combined by q^4
    float accE = Pe[tid];
    float accO = Pe[tid + 1];
    #pragma unroll
    for (int j = 2; j <= 24; j += 2) accE = fmaf(accE, q8, Pe[tid + j]);
    #pragma unroll
    for (int j = 3; j <= 23; j += 2) accO = fmaf(accO, q8, Pe[tid + j]);
    float M = w0 * fmaf(q4, accO, accE);   // == M[t0-1]

    // ---- 4-step recursion + gain; output is one coalesced float4 ----
    f32x4 o;
    M = fmaf(q, M, fmaf(w0, a0, -c3 * b0));
    o.x = gain_div(v.x, M, alpha);
    M = fmaf(q, M, fmaf(w0, a1, -c3 * b1));
    o.y = gain_div(v.y, M, alpha);
    M = fmaf(q, M, fmaf(w0, a2, -c3 * b2));
    o.z = gain_div(v.z, M, alpha);
    M = fmaf(q, M, fmaf(w0, a3, -c3 * b3));
    o.w = gain_div(v.w, M, alpha);

    __builtin_nontemporal_store(o, &reinterpret_cast<f32x4*>(orow)[i4]);
}

extern "C" void kernel_launch(void* const* d_in, const int* in_sizes, int n_in,
                              void* d_out, int out_size, void* d_ws, size_t ws_size,
                              hipStream_t stream) {
    const float* x         = (const float*)d_in[0];
    const float* alpha_raw = (const float*)d_in[1];
    const float* log_s     = (const float*)d_in[2];
    float* out             = (float*)d_out;
    const int nrows = in_sizes[0] / T;   // B*KC = 4096
    agc_kernel<<<nrows * NSEG, BLOCK, 0, stream>>>(x, alpha_raw, log_s, out);
}